// Round 13
// baseline (33.415 us; speedup 1.0000x reference)
//
#include <hip/hip_runtime.h>

// out[b,i,j,c] = sum_d tanh(start[b,c,i,d] + end[b,c,j,d]) * v[d]
// B=2, C=8, L=256, D=128.
//
// tanh(x) = 1 - 2/(e^{2x}+1);  e^{2(s+e)} = Es*Ee.  With W_d = -0.5/v_d and
// staged Es' = Es*W_d:  u_d = fma(Es',Ee,W_d) = -0.5*q_d/v_d  (q_d = EsEe+1),
// out = sum(v) + sum_d 1/u_d; per d-quad the four 1/u merge into ONE rcp:
//   [cd*(u0+u1) + ab*(u2+u3)] * rcp(ab*cd).
//
// R13: TWO-PASS. Pass 1 precomputes the Es'/Ee tables to d_ws ONCE (1M exp2
// instead of 8M: every row was previously re-exp2'd by 8 blocks). Pass 2 =
// R10's inner loop but S/E read straight from the L2-resident tables via
// global_load_dwordx4 (VMEM pipe, co-issues with VALU; no tile staging, no
// staging barriers, LDS only for the park reduction + W). Fallback to the
// proven R10 single-pass kernel if ws_size < 4 MB.

#define LDIM 256
#define DDIM 128
#define TBL_ELEMS (2 * 8 * 256 * 128)     // 524288 f32 per table
#define KLOG2E 2.8853900817779268f        // 2*log2(e)

// ---------------- pass 1: table precompute ----------------
__global__ __launch_bounds__(256) void precompute_kernel(
    const float* __restrict__ s_in,
    const float* __restrict__ e_in,
    const float* __restrict__ v,
    float* __restrict__ ws)
{
    const int i = blockIdx.x * 256 + threadIdx.x;    // 0..131071 float4 chunks
    const int c4 = (i & 31) << 2;                    // d-quad = (4i) % 128
    const float4 vv = *(const float4*)(v + c4);
    const float w0 = -0.5f * __builtin_amdgcn_rcpf(vv.x);
    const float w1 = -0.5f * __builtin_amdgcn_rcpf(vv.y);
    const float w2 = -0.5f * __builtin_amdgcn_rcpf(vv.z);
    const float w3 = -0.5f * __builtin_amdgcn_rcpf(vv.w);

    float4 a = *(const float4*)(s_in + 4 * (size_t)i);
    float4 o;
    o.x = __builtin_amdgcn_exp2f(KLOG2E * a.x) * w0;
    o.y = __builtin_amdgcn_exp2f(KLOG2E * a.y) * w1;
    o.z = __builtin_amdgcn_exp2f(KLOG2E * a.z) * w2;
    o.w = __builtin_amdgcn_exp2f(KLOG2E * a.w) * w3;
    *(float4*)(ws + 4 * (size_t)i) = o;

    float4 b = *(const float4*)(e_in + 4 * (size_t)i);
    float4 p;
    p.x = __builtin_amdgcn_exp2f(KLOG2E * b.x);
    p.y = __builtin_amdgcn_exp2f(KLOG2E * b.y);
    p.z = __builtin_amdgcn_exp2f(KLOG2E * b.z);
    p.w = __builtin_amdgcn_exp2f(KLOG2E * b.w);
    *(float4*)(ws + TBL_ELEMS + 4 * (size_t)i) = p;
}

// ---------------- pass 2: main, tables from global ----------------
__global__ __launch_bounds__(256) void span_main_kernel(
    const float* __restrict__ ws,
    const float* __restrict__ v,
    float* __restrict__ out,
    int C)
{
    __shared__ float red[4096];     // 16 KB park buffer
    __shared__ float W_s[DDIM];     // -0.5 / v[d]
    __shared__ float s_vsum;

    const int bc = blockIdx.z;
    const int i0 = blockIdx.y * 32;
    const int j0 = blockIdx.x * 32;
    const int tx = threadIdx.x;               // 0..7
    const int ty = threadIdx.y;               // 0..7
    const int g  = threadIdx.z;               // 0..3: wave = d-quarter
    const int t  = ty * 8 + tx;
    const int tid = g * 64 + t;

    if (tid < 32) {
        const float4 vv = *(const float4*)(v + 4 * tid);
        float4 w;
        w.x = -0.5f * __builtin_amdgcn_rcpf(vv.x);
        w.y = -0.5f * __builtin_amdgcn_rcpf(vv.y);
        w.z = -0.5f * __builtin_amdgcn_rcpf(vv.z);
        w.w = -0.5f * __builtin_amdgcn_rcpf(vv.w);
        *(float4*)(&W_s[4 * tid]) = w;
    }
    if (g == 0) {
        float2 vv = *(const float2*)(v + 2 * t);
        float p = vv.x + vv.y;
        #pragma unroll
        for (int off = 1; off < 64; off <<= 1) p += __shfl_xor(p, off);
        if (t == 0) s_vsum = p;
    }
    __syncthreads();

    const int dbase = __builtin_amdgcn_readfirstlane(g) * 32;
    const float* Sb = ws + (size_t)bc * (LDIM * DDIM) + (i0 + ty) * DDIM;
    const float* Eb = ws + TBL_ELEMS + (size_t)bc * (LDIM * DDIM) + (j0 + tx) * DDIM;

    float acc00 = 0.f, acc01 = 0.f, acc02 = 0.f, acc03 = 0.f;
    float acc10 = 0.f, acc11 = 0.f, acc12 = 0.f, acc13 = 0.f;
    float acc20 = 0.f, acc21 = 0.f, acc22 = 0.f, acc23 = 0.f;
    float acc30 = 0.f, acc31 = 0.f, acc32 = 0.f, acc33 = 0.f;

#define QUAD(ACC, S, E)                                            \
    {                                                              \
        float u0 = fmaf((S).x, (E).x, W.x);                        \
        float u1 = fmaf((S).y, (E).y, W.y);                        \
        float u2 = fmaf((S).z, (E).z, W.z);                        \
        float u3 = fmaf((S).w, (E).w, W.w);                        \
        float ab = u0 * u1, cd = u2 * u3;                          \
        float n01 = u0 + u1;                                       \
        float n23 = u2 + u3;                                       \
        float N = fmaf(n01, cd, n23 * ab);                         \
        float r = __builtin_amdgcn_rcpf(ab * cd);                  \
        ACC = fmaf(N, r, ACC);                                     \
    }

    #pragma unroll 2
    for (int it = 0; it < 8; ++it) {
        const int d = dbase + it * 4;
        const float4 s0 = *(const float4*)(Sb + d);                 // L2-resident
        const float4 s1 = *(const float4*)(Sb +  8 * DDIM + d);
        const float4 s2 = *(const float4*)(Sb + 16 * DDIM + d);
        const float4 s3 = *(const float4*)(Sb + 24 * DDIM + d);
        const float4 e0 = *(const float4*)(Eb + d);
        const float4 e1 = *(const float4*)(Eb +  8 * DDIM + d);
        const float4 e2 = *(const float4*)(Eb + 16 * DDIM + d);
        const float4 e3 = *(const float4*)(Eb + 24 * DDIM + d);
        const float4 W  = *(const float4*)(&W_s[d]);                // broadcast

        QUAD(acc00, s0, e0); QUAD(acc01, s0, e1); QUAD(acc02, s0, e2); QUAD(acc03, s0, e3);
        QUAD(acc10, s1, e0); QUAD(acc11, s1, e1); QUAD(acc12, s1, e2); QUAD(acc13, s1, e3);
        QUAD(acc20, s2, e0); QUAD(acc21, s2, e1); QUAD(acc22, s2, e2); QUAD(acc23, s2, e3);
        QUAD(acc30, s3, e0); QUAD(acc31, s3, e1); QUAD(acc32, s3, e2); QUAD(acc33, s3, e3);
    }
#undef QUAD

    // cross-wave d-reduction: lane-stride-1 slots (2 words/bank = free)
#define PARK(A, B, ACC) red[(((A) * 4 + (B)) * 4 + g) * 64 + t] = ACC;
    PARK(0,0,acc00) PARK(0,1,acc01) PARK(0,2,acc02) PARK(0,3,acc03)
    PARK(1,0,acc10) PARK(1,1,acc11) PARK(1,2,acc12) PARK(1,3,acc13)
    PARK(2,0,acc20) PARK(2,1,acc21) PARK(2,2,acc22) PARK(2,3,acc23)
    PARK(3,0,acc30) PARK(3,1,acc31) PARK(3,2,acc32) PARK(3,3,acc33)
#undef PARK
    __syncthreads();

#define COMB(B)                                                    \
    (red[((g * 4 + (B)) * 4 + 0) * 64 + t] +                       \
     red[((g * 4 + (B)) * 4 + 1) * 64 + t] +                       \
     red[((g * 4 + (B)) * 4 + 2) * 64 + t] +                       \
     red[((g * 4 + (B)) * 4 + 3) * 64 + t])
    const float o0 = COMB(0);
    const float o1 = COMB(1);
    const float o2 = COMB(2);
    const float o3 = COMB(3);
#undef COMB

    const int b_ = bc / C;
    const int c_ = bc - b_ * C;
    const float Sv = s_vsum;
    const int i = i0 + ty + 8 * g;
    const size_t rowbase = (((size_t)b_ * LDIM + i) * LDIM) * C + c_;
    out[rowbase + (size_t)(j0 + tx     ) * C] = Sv + o0;
    out[rowbase + (size_t)(j0 + tx +  8) * C] = Sv + o1;
    out[rowbase + (size_t)(j0 + tx + 16) * C] = Sv + o2;
    out[rowbase + (size_t)(j0 + tx + 24) * C] = Sv + o3;
}

// ---------------- fallback: R10 single-pass (proven 18.39 us) ----------------
#define DPAD 132

__global__ __launch_bounds__(256) void span_fallback_kernel(
    const float* __restrict__ start_h,
    const float* __restrict__ end_h,
    const float* __restrict__ v,
    float* __restrict__ out,
    int C)
{
    __shared__ float s_pool[32 * DPAD];
    __shared__ float e_t[32][DPAD];
    __shared__ float s_vsum;
    float (*s_t)[DPAD] = (float (*)[DPAD])s_pool;

    const int bc = blockIdx.z;
    const int i0 = blockIdx.y * 32;
    const int j0 = blockIdx.x * 32;
    const int tx = threadIdx.x, ty = threadIdx.y, g = threadIdx.z;
    const int t = ty * 8 + tx;
    const int tid = g * 64 + t;

    const float* sg = start_h + ((size_t)bc * LDIM + i0) * DDIM;
    const float* eg = end_h   + ((size_t)bc * LDIM + j0) * DDIM;

    #pragma unroll
    for (int k = 0; k < 4; ++k) {
        const int idx = tid + k * 256;
        const int r  = idx >> 5;
        const int c4 = (idx & 31) << 2;
        const float4 vv = *(const float4*)(v + c4);
        float4 a = *(const float4*)(sg + r * DDIM + c4);
        a.x = __builtin_amdgcn_exp2f(KLOG2E * a.x) * (-0.5f * __builtin_amdgcn_rcpf(vv.x));
        a.y = __builtin_amdgcn_exp2f(KLOG2E * a.y) * (-0.5f * __builtin_amdgcn_rcpf(vv.y));
        a.z = __builtin_amdgcn_exp2f(KLOG2E * a.z) * (-0.5f * __builtin_amdgcn_rcpf(vv.z));
        a.w = __builtin_amdgcn_exp2f(KLOG2E * a.w) * (-0.5f * __builtin_amdgcn_rcpf(vv.w));
        *(float4*)(&s_t[r][c4]) = a;
        float4 b = *(const float4*)(eg + r * DDIM + c4);
        b.x = __builtin_amdgcn_exp2f(KLOG2E * b.x);
        b.y = __builtin_amdgcn_exp2f(KLOG2E * b.y);
        b.z = __builtin_amdgcn_exp2f(KLOG2E * b.z);
        b.w = __builtin_amdgcn_exp2f(KLOG2E * b.w);
        *(float4*)(&e_t[r][c4]) = b;
    }
    if (g == 0) {
        float2 vv = *(const float2*)(v + 2 * t);
        float p = vv.x + vv.y;
        #pragma unroll
        for (int off = 1; off < 64; off <<= 1) p += __shfl_xor(p, off);
        if (t == 0) s_vsum = p;
    }
    __syncthreads();

    const int dbase = __builtin_amdgcn_readfirstlane(g) * 32;
    float acc00 = 0.f, acc01 = 0.f, acc02 = 0.f, acc03 = 0.f;
    float acc10 = 0.f, acc11 = 0.f, acc12 = 0.f, acc13 = 0.f;
    float acc20 = 0.f, acc21 = 0.f, acc22 = 0.f, acc23 = 0.f;
    float acc30 = 0.f, acc31 = 0.f, acc32 = 0.f, acc33 = 0.f;

#define QUAD(ACC, S, E, WV)                                        \
    {                                                              \
        float u0 = fmaf((S).x, (E).x, (WV).x);                     \
        float u1 = fmaf((S).y, (E).y, (WV).y);                     \
        float u2 = fmaf((S).z, (E).z, (WV).z);                     \
        float u3 = fmaf((S).w, (E).w, (WV).w);                     \
        float ab = u0 * u1, cd = u2 * u3;                          \
        float n01 = u0 + u1;                                       \
        float n23 = u2 + u3;                                       \
        float N = fmaf(n01, cd, n23 * ab);                         \
        float r = __builtin_amdgcn_rcpf(ab * cd);                  \
        ACC = fmaf(N, r, ACC);                                     \
    }

    #pragma unroll 2
    for (int it = 0; it < 8; ++it) {
        const int d = dbase + it * 4;
        const float4 vv = *(const float4*)(v + d);
        float4 W;
        W.x = -0.5f * __builtin_amdgcn_rcpf(vv.x);
        W.y = -0.5f * __builtin_amdgcn_rcpf(vv.y);
        W.z = -0.5f * __builtin_amdgcn_rcpf(vv.z);
        W.w = -0.5f * __builtin_amdgcn_rcpf(vv.w);
        const float4 s0 = *(const float4*)(&s_t[ty     ][d]);
        const float4 s1 = *(const float4*)(&s_t[ty +  8][d]);
        const float4 s2 = *(const float4*)(&s_t[ty + 16][d]);
        const float4 s3 = *(const float4*)(&s_t[ty + 24][d]);
        const float4 e0 = *(const float4*)(&e_t[tx     ][d]);
        const float4 e1 = *(const float4*)(&e_t[tx +  8][d]);
        const float4 e2 = *(const float4*)(&e_t[tx + 16][d]);
        const float4 e3 = *(const float4*)(&e_t[tx + 24][d]);

        QUAD(acc00, s0, e0, W); QUAD(acc01, s0, e1, W); QUAD(acc02, s0, e2, W); QUAD(acc03, s0, e3, W);
        QUAD(acc10, s1, e0, W); QUAD(acc11, s1, e1, W); QUAD(acc12, s1, e2, W); QUAD(acc13, s1, e3, W);
        QUAD(acc20, s2, e0, W); QUAD(acc21, s2, e1, W); QUAD(acc22, s2, e2, W); QUAD(acc23, s2, e3, W);
        QUAD(acc30, s3, e0, W); QUAD(acc31, s3, e1, W); QUAD(acc32, s3, e2, W); QUAD(acc33, s3, e3, W);
    }
#undef QUAD

    __syncthreads();
    float* red = s_pool;
#define PARK(A, B, ACC) red[(((A) * 4 + (B)) * 4 + g) * 64 + t] = ACC;
    PARK(0,0,acc00) PARK(0,1,acc01) PARK(0,2,acc02) PARK(0,3,acc03)
    PARK(1,0,acc10) PARK(1,1,acc11) PARK(1,2,acc12) PARK(1,3,acc13)
    PARK(2,0,acc20) PARK(2,1,acc21) PARK(2,2,acc22) PARK(2,3,acc23)
    PARK(3,0,acc30) PARK(3,1,acc31) PARK(3,2,acc32) PARK(3,3,acc33)
#undef PARK
    __syncthreads();
#define COMB(B)                                                    \
    (red[((g * 4 + (B)) * 4 + 0) * 64 + t] +                       \
     red[((g * 4 + (B)) * 4 + 1) * 64 + t] +                       \
     red[((g * 4 + (B)) * 4 + 2) * 64 + t] +                       \
     red[((g * 4 + (B)) * 4 + 3) * 64 + t])
    const float o0 = COMB(0);
    const float o1 = COMB(1);
    const float o2 = COMB(2);
    const float o3 = COMB(3);
#undef COMB

    const int b_ = bc / C;
    const int c_ = bc - b_ * C;
    const float Sv = s_vsum;
    const int i = i0 + ty + 8 * g;
    const size_t rowbase = (((size_t)b_ * LDIM + i) * LDIM) * C + c_;
    out[rowbase + (size_t)(j0 + tx     ) * C] = Sv + o0;
    out[rowbase + (size_t)(j0 + tx +  8) * C] = Sv + o1;
    out[rowbase + (size_t)(j0 + tx + 16) * C] = Sv + o2;
    out[rowbase + (size_t)(j0 + tx + 24) * C] = Sv + o3;
}

extern "C" void kernel_launch(void* const* d_in, const int* in_sizes, int n_in,
                              void* d_out, int out_size, void* d_ws, size_t ws_size,
                              hipStream_t stream) {
    const float* start_h = (const float*)d_in[0];
    const float* end_h   = (const float*)d_in[1];
    const float* v       = (const float*)d_in[2];
    float* out = (float*)d_out;

    const int BC = in_sizes[0] / (LDIM * DDIM);  // B*C = 16
    const int C  = 8;
    const size_t ws_needed = (size_t)2 * TBL_ELEMS * sizeof(float);  // 4 MB

    if (ws_size >= ws_needed && d_ws != nullptr) {
        float* ws = (float*)d_ws;
        precompute_kernel<<<TBL_ELEMS / 4 / 256, 256, 0, stream>>>(start_h, end_h, v, ws);
        dim3 grid(LDIM / 32, LDIM / 32, BC);
        dim3 block(8, 8, 4);
        span_main_kernel<<<grid, block, 0, stream>>>(ws, v, out, C);
    } else {
        dim3 grid(LDIM / 32, LDIM / 32, BC);
        dim3 block(8, 8, 4);
        span_fallback_kernel<<<grid, block, 0, stream>>>(start_h, end_h, v, out, C);
    }
}

// Round 14
// 18.301 us; speedup vs baseline: 1.8259x; 1.8259x over previous
//
#include <hip/hip_runtime.h>

// out[b,i,j,c] = sum_d tanh(start[b,c,i,d] + end[b,c,j,d]) * v[d]
// B=2, C=8, L=256, D=128.
//
// tanh(x) = 1 - 2/(e^{2x}+1);  e^{2(s+e)} = Es*Ee, Es=exp2(K*s), K=2*log2(e).
// u-substitution (R10): w_d = 1/v_d, stage Es' = Es*w_d, then
//   u_d = fma(Es',Ee,w_d) = q_d*w_d  and  sum_d v_d/q_d = sum_d 1/u_d
//   = [cd*(u0+u1) + ab*(u2+u3)] / (ab*cd)
// -> numerator pairs are ADDs, not fma+mul: 11 full-rate + 1 rcp per 4 elems.
// out = sum(v) - 2 * sum_d 1/u_d.
//
// BEST MEASURED: 18.39 us (round 10). Restored verbatim after the R13
// two-pass regression (33.4 us: pass-2 VMEM scatter + no LDS reuse).
// 13-round evidence: occupancy/LDS-traffic/two-pass/big-tile levers all
// null or negative; this structure sits at the sum-of-pipes floor.

#define LDIM 256
#define DDIM 128
#define DPAD 132   // 132 mod 32 = 4 -> rows ty+8k start at bank 4*ty: conflict-free

__global__ __launch_bounds__(256) void span_tanh_dot_kernel(
    const float* __restrict__ start_h,
    const float* __restrict__ end_h,
    const float* __restrict__ v,
    float* __restrict__ out,
    int C)
{
    __shared__ float s_pool[32 * DPAD];      // Es' tile (+w pad); later reduction buf
    __shared__ float e_t[32][DPAD];          // Ee tile
    __shared__ float s_vsum;
    float (*s_t)[DPAD] = (float (*)[DPAD])s_pool;

    const int bc = blockIdx.z;               // b*C + c
    const int i0 = blockIdx.y * 32;
    const int j0 = blockIdx.x * 32;
    const int tx = threadIdx.x;              // 0..7
    const int ty = threadIdx.y;              // 0..7
    const int g  = threadIdx.z;              // 0..3: wave = d-quarter
    const int t  = ty * 8 + tx;              // lane in wave
    const int tid = g * 64 + t;

    const float K = 2.8853900817779268f;     // 2*log2(e)

    const float* sg = start_h + ((size_t)bc * LDIM + i0) * DDIM;
    const float* eg = end_h   + ((size_t)bc * LDIM + j0) * DDIM;

    // stage 32x128 tiles: s_t = exp2(K*s)/v_d ; e_t = exp2(K*e)
    #pragma unroll
    for (int k = 0; k < 4; ++k) {
        const int idx = tid + k * 256;
        const int r  = idx >> 5;
        const int c4 = (idx & 31) << 2;
        const float4 vv = *(const float4*)(v + c4);
        const float w0 = __builtin_amdgcn_rcpf(vv.x);
        const float w1 = __builtin_amdgcn_rcpf(vv.y);
        const float w2 = __builtin_amdgcn_rcpf(vv.z);
        const float w3 = __builtin_amdgcn_rcpf(vv.w);
        float4 a = *(const float4*)(sg + r * DDIM + c4);
        a.x = __builtin_amdgcn_exp2f(K * a.x) * w0;
        a.y = __builtin_amdgcn_exp2f(K * a.y) * w1;
        a.z = __builtin_amdgcn_exp2f(K * a.z) * w2;
        a.w = __builtin_amdgcn_exp2f(K * a.w) * w3;
        *(float4*)(&s_t[r][c4]) = a;
        float4 b = *(const float4*)(eg + r * DDIM + c4);
        b.x = __builtin_amdgcn_exp2f(K * b.x);
        b.y = __builtin_amdgcn_exp2f(K * b.y);
        b.z = __builtin_amdgcn_exp2f(K * b.z);
        b.w = __builtin_amdgcn_exp2f(K * b.w);
        *(float4*)(&e_t[r][c4]) = b;
    }

    // w table into the unused pad cols of s_t: w[d] at s_t[d>>2][128+(d&3)]
    if (tid < 128) {
        s_t[tid >> 2][128 + (tid & 3)] = __builtin_amdgcn_rcpf(v[tid]);
    }

    // sum(v): wave 0 butterfly -> LDS broadcast
    if (g == 0) {
        float2 vv = *(const float2*)(v + 2 * t);
        float p = vv.x + vv.y;
        #pragma unroll
        for (int off = 1; off < 64; off <<= 1) p += __shfl_xor(p, off);
        if (t == 0) s_vsum = p;
    }
    __syncthreads();

    const int g8 = __builtin_amdgcn_readfirstlane(g) * 8;  // wave-uniform row base

    float acc00 = 0.f, acc01 = 0.f, acc02 = 0.f, acc03 = 0.f;
    float acc10 = 0.f, acc11 = 0.f, acc12 = 0.f, acc13 = 0.f;
    float acc20 = 0.f, acc21 = 0.f, acc22 = 0.f, acc23 = 0.f;
    float acc30 = 0.f, acc31 = 0.f, acc32 = 0.f, acc33 = 0.f;

#define QUAD(ACC, S, E)                                            \
    {                                                              \
        float u0 = fmaf((S).x, (E).x, W.x);                        \
        float u1 = fmaf((S).y, (E).y, W.y);                        \
        float u2 = fmaf((S).z, (E).z, W.z);                        \
        float u3 = fmaf((S).w, (E).w, W.w);                        \
        float ab = u0 * u1, cd = u2 * u3;                          \
        float n01 = u0 + u1;                                       \
        float n23 = u2 + u3;                                       \
        float N = fmaf(n01, cd, n23 * ab);                         \
        float r = __builtin_amdgcn_rcpf(ab * cd);                  \
        ACC = fmaf(N, r, ACC);                                     \
    }

    #pragma unroll 2
    for (int it = 0; it < 8; ++it) {
        const int d = (g8 + it) * 4;
        const float4 W  = *(const float4*)(&s_t[g8 + it][128]);   // broadcast: free
        const float4 s0 = *(const float4*)(&s_t[ty     ][d]);     // banks 4ty: free
        const float4 s1 = *(const float4*)(&s_t[ty +  8][d]);
        const float4 s2 = *(const float4*)(&s_t[ty + 16][d]);
        const float4 s3 = *(const float4*)(&s_t[ty + 24][d]);
        const float4 e0 = *(const float4*)(&e_t[tx     ][d]);
        const float4 e1 = *(const float4*)(&e_t[tx +  8][d]);
        const float4 e2 = *(const float4*)(&e_t[tx + 16][d]);
        const float4 e3 = *(const float4*)(&e_t[tx + 24][d]);

        QUAD(acc00, s0, e0); QUAD(acc01, s0, e1); QUAD(acc02, s0, e2); QUAD(acc03, s0, e3);
        QUAD(acc10, s1, e0); QUAD(acc11, s1, e1); QUAD(acc12, s1, e2); QUAD(acc13, s1, e3);
        QUAD(acc20, s2, e0); QUAD(acc21, s2, e1); QUAD(acc22, s2, e2); QUAD(acc23, s2, e3);
        QUAD(acc30, s3, e0); QUAD(acc31, s3, e1); QUAD(acc32, s3, e2); QUAD(acc33, s3, e3);
    }
#undef QUAD

    // ---- conflict-free cross-wave d-reduction, aliased into s_t ----
    // slot(a,b,src,t) = ((a*4+b)*4 + src)*64 + t : lane stride 1 word (free)
    __syncthreads();                        // everyone done reading s_t
    float* red = s_pool;
#define PARK(A, B, ACC) red[(((A) * 4 + (B)) * 4 + g) * 64 + t] = ACC;
    PARK(0,0,acc00) PARK(0,1,acc01) PARK(0,2,acc02) PARK(0,3,acc03)
    PARK(1,0,acc10) PARK(1,1,acc11) PARK(1,2,acc12) PARK(1,3,acc13)
    PARK(2,0,acc20) PARK(2,1,acc21) PARK(2,2,acc22) PARK(2,3,acc23)
    PARK(3,0,acc30) PARK(3,1,acc31) PARK(3,2,acc32) PARK(3,3,acc33)
#undef PARK
    __syncthreads();

    // wave g combines row-group a = g (4 b32 reads per output, stride-1 lanes)
#define COMB(B)                                                    \
    (red[((g * 4 + (B)) * 4 + 0) * 64 + t] +                       \
     red[((g * 4 + (B)) * 4 + 1) * 64 + t] +                       \
     red[((g * 4 + (B)) * 4 + 2) * 64 + t] +                       \
     red[((g * 4 + (B)) * 4 + 3) * 64 + t])
    const float o0 = COMB(0);
    const float o1 = COMB(1);
    const float o2 = COMB(2);
    const float o3 = COMB(3);
#undef COMB

    const int b_ = bc / C;
    const int c_ = bc - b_ * C;
    const float Sv = s_vsum;
    const int i = i0 + ty + 8 * g;
    const size_t rowbase = (((size_t)b_ * LDIM + i) * LDIM) * C + c_;
    out[rowbase + (size_t)(j0 + tx     ) * C] = fmaf(-2.f, o0, Sv);
    out[rowbase + (size_t)(j0 + tx +  8) * C] = fmaf(-2.f, o1, Sv);
    out[rowbase + (size_t)(j0 + tx + 16) * C] = fmaf(-2.f, o2, Sv);
    out[rowbase + (size_t)(j0 + tx + 24) * C] = fmaf(-2.f, o3, Sv);
}

extern "C" void kernel_launch(void* const* d_in, const int* in_sizes, int n_in,
                              void* d_out, int out_size, void* d_ws, size_t ws_size,
                              hipStream_t stream) {
    const float* start_h = (const float*)d_in[0];
    const float* end_h   = (const float*)d_in[1];
    const float* v       = (const float*)d_in[2];
    float* out = (float*)d_out;

    const int BC = in_sizes[0] / (LDIM * DDIM);  // B*C = 16
    const int C  = 8;

    dim3 grid(LDIM / 32, LDIM / 32, BC);   // (8, 8, 16) = 1024 blocks, 4/CU
    dim3 block(8, 8, 4);                   // 256 threads; wave g = d-quarter
    span_tanh_dot_kernel<<<grid, block, 0, stream>>>(start_h, end_h, v, out, C);
}